// Round 4
// baseline (264.782 us; speedup 1.0000x reference)
//
#include <hip/hip_runtime.h>
#include <hip/hip_bf16.h>

#define U_CNT 50000
#define I_CNT 25000
#define D_DIM 128
#define E_CNT 1000000
#define B_CNT 4096
#define ICAP 96   // max item degree ~68 (Poisson 40, 25K draws)
#define UCAP 64   // max user degree ~48 (Poisson 20, 50K draws)

// ---------------------------------------------------------------------------
// ws layout:
//   flags [U] int      : 0 or rep_slot+1 for sampled users   (zeroed)
//   icnt  [I] int      : per-item degree / bucket count      (zeroed)
//   ucnt  [B] int      : per-rep-slot bucket count           (zeroed)
//   udeg  [U] int      : user degrees                        (zeroed)
//   dinv_u[U] float, dinv_i[I] float
//   ibuck [I*ICAP] int : neighbor user ids
//   ubuck [B*UCAP] int : neighbor item ids
//   ue16  [U*64] u32   : user_emb in packed bf16x2 (256 B/row)
//   ie16  [I*64] u32   : item_emb in packed bf16x2
// total ~30.6 MB.  adj_vals never read: val = dinv_u[u]*dinv_i[t].
// ---------------------------------------------------------------------------

__device__ __forceinline__ unsigned pack_bf2(float lo, float hi) {
    __hip_bfloat16 a = __float2bfloat16(lo);   // RNE
    __hip_bfloat16 b = __float2bfloat16(hi);
    unsigned short ua = *reinterpret_cast<unsigned short*>(&a);
    unsigned short ub = *reinterpret_cast<unsigned short*>(&b);
    return ((unsigned)ub << 16) | ua;
}
__device__ __forceinline__ float bf_lo(unsigned w) { return __uint_as_float(w << 16); }
__device__ __forceinline__ float bf_hi(unsigned w) { return __uint_as_float(w & 0xffff0000u); }

__global__ void rep_kernel(const int* __restrict__ users, int* __restrict__ flags) {
    int j = blockIdx.x * blockDim.x + threadIdx.x;
    if (j < B_CNT) atomicCAS(&flags[users[j]], 0, j + 1);
}

// fp32 -> packed bf16x2, one output dword per thread (streaming)
__global__ __launch_bounds__(256) void cvt_kernel(
        const float* __restrict__ src, unsigned* __restrict__ dst, int n_dw) {
    int i = blockIdx.x * blockDim.x + threadIdx.x;
    if (i >= n_dw) return;
    float2 f = ((const float2*)src)[i];
    dst[i] = pack_bf2(f.x, f.y);
}

// one pass over the E undirected edges (mirror half is redundant):
// count degrees on both sides, place ids into fixed-capacity buckets.
__global__ __launch_bounds__(256) void bucket_kernel(
        const int* __restrict__ adj_row,
        const int* __restrict__ adj_col,
        const int* __restrict__ flags,
        int* __restrict__ icnt, int* __restrict__ ucnt, int* __restrict__ udeg,
        int* __restrict__ ibuck, int* __restrict__ ubuck) {
    const int base = (blockIdx.x * blockDim.x + threadIdx.x) * 2;
    if (base >= E_CNT) return;
    const int2 uu = *(const int2*)(adj_row + base);
    const int2 tt = *(const int2*)(adj_col + base);
#pragma unroll
    for (int k = 0; k < 2; ++k) {
        const int u = k ? uu.y : uu.x;
        const int t = (k ? tt.y : tt.x) - U_CNT;
        atomicAdd(&udeg[u], 1);
        const int c = atomicAdd(&icnt[t], 1);
        ibuck[(size_t)t * ICAP + c] = u;
        const int f = flags[u];
        if (f) {
            const int j0 = f - 1;
            const int c2 = atomicAdd(&ucnt[j0], 1);
            ubuck[(size_t)j0 * UCAP + c2] = t;
        }
    }
}

__global__ void dinv_kernel(const int* __restrict__ udeg, const int* __restrict__ icnt,
                            float* __restrict__ dinv_u, float* __restrict__ dinv_i) {
    int i = blockIdx.x * blockDim.x + threadIdx.x;
    if (i < U_CNT) { int d = udeg[i]; dinv_u[i] = d > 0 ? 1.0f / sqrtf((float)d) : 0.0f; }
    if (i < I_CNT) { int d = icnt[i]; dinv_i[i] = d > 0 ? 1.0f / sqrtf((float)d) : 0.0f; }
}

// one wave per item: bf16 row gathers (one dword/lane), fp32 accumulate,
// fused epilogue (ego stays fp32-exact).
__global__ __launch_bounds__(256) void item_gather_kernel(
        const float*    __restrict__ item_emb,
        const unsigned* __restrict__ ue16,
        const int*      __restrict__ icnt,
        const float*    __restrict__ dinv_u,
        const float*    __restrict__ dinv_i,
        const int*      __restrict__ ibuck,
        float*          __restrict__ out) {
    const int lane = threadIdx.x & 63;
    const int t    = (blockIdx.x * blockDim.x + threadIdx.x) >> 6;
    if (t >= I_CNT) return;

    const int   n  = icnt[t];
    const float dt = dinv_i[t];
    const int*  b  = ibuck + (size_t)t * ICAP;
    float ax = 0.0f, ay = 0.0f;

    int p = 0;
    for (; p + 4 <= n; p += 4) {
        const int u0 = b[p], u1 = b[p + 1], u2 = b[p + 2], u3 = b[p + 3];
        const unsigned w0 = ue16[(size_t)u0 * 64 + lane];
        const unsigned w1 = ue16[(size_t)u1 * 64 + lane];
        const unsigned w2 = ue16[(size_t)u2 * 64 + lane];
        const unsigned w3 = ue16[(size_t)u3 * 64 + lane];
        const float v0 = dt * dinv_u[u0], v1 = dt * dinv_u[u1];
        const float v2 = dt * dinv_u[u2], v3 = dt * dinv_u[u3];
        ax += v0 * bf_lo(w0) + v1 * bf_lo(w1) + v2 * bf_lo(w2) + v3 * bf_lo(w3);
        ay += v0 * bf_hi(w0) + v1 * bf_hi(w1) + v2 * bf_hi(w2) + v3 * bf_hi(w3);
    }
    for (; p < n; ++p) {
        const int u = b[p];
        const unsigned w = ue16[(size_t)u * 64 + lane];
        const float v = dt * dinv_u[u];
        ax += v * bf_lo(w);
        ay += v * bf_hi(w);
    }

    const float2 eg = ((const float2*)(item_emb + (size_t)t * D_DIM))[lane];
    float2 o;
    o.x = (eg.x + 3.0f * ax) * 0.25f;
    o.y = (eg.y + 3.0f * ay) * 0.25f;
    ((float2*)(out + (size_t)(3 * B_CNT + t) * D_DIM))[lane] = o;
}

// one wave per output slot (representatives compute; dups copied in finalize)
__global__ __launch_bounds__(256) void user_gather_kernel(
        const float*    __restrict__ user_emb,
        const unsigned* __restrict__ ie16,
        const int*      __restrict__ users,
        const int*      __restrict__ flags,
        const int*      __restrict__ ucnt,
        const float*    __restrict__ dinv_u,
        const float*    __restrict__ dinv_i,
        const int*      __restrict__ ubuck,
        float*          __restrict__ out) {
    const int lane = threadIdx.x & 63;
    const int j    = (blockIdx.x * blockDim.x + threadIdx.x) >> 6;
    if (j >= B_CNT) return;
    const int u = users[j];
    if (flags[u] - 1 != j) return;

    const int   n  = ucnt[j];
    const float du = dinv_u[u];
    const int*  b  = ubuck + (size_t)j * UCAP;
    float ax = 0.0f, ay = 0.0f;

    int p = 0;
    for (; p + 4 <= n; p += 4) {
        const int t0 = b[p], t1 = b[p + 1], t2 = b[p + 2], t3 = b[p + 3];
        const unsigned w0 = ie16[(size_t)t0 * 64 + lane];
        const unsigned w1 = ie16[(size_t)t1 * 64 + lane];
        const unsigned w2 = ie16[(size_t)t2 * 64 + lane];
        const unsigned w3 = ie16[(size_t)t3 * 64 + lane];
        const float v0 = du * dinv_i[t0], v1 = du * dinv_i[t1];
        const float v2 = du * dinv_i[t2], v3 = du * dinv_i[t3];
        ax += v0 * bf_lo(w0) + v1 * bf_lo(w1) + v2 * bf_lo(w2) + v3 * bf_lo(w3);
        ay += v0 * bf_hi(w0) + v1 * bf_hi(w1) + v2 * bf_hi(w2) + v3 * bf_hi(w3);
    }
    for (; p < n; ++p) {
        const int t = b[p];
        const unsigned w = ie16[(size_t)t * 64 + lane];
        const float v = du * dinv_i[t];
        ax += v * bf_lo(w);
        ay += v * bf_hi(w);
    }

    const float2 eg = ((const float2*)(user_emb + (size_t)u * D_DIM))[lane];
    float2 o;
    o.x = (eg.x + 3.0f * ax) * 0.25f;
    o.y = (eg.y + 3.0f * ay) * 0.25f;
    ((float2*)(out + (size_t)j * D_DIM))[lane] = o;
}

__global__ __launch_bounds__(256) void finalize_kernel(
        const int* __restrict__ users,
        const int* __restrict__ flags,
        const int* __restrict__ pos_items,
        const int* __restrict__ neg_items,
        float*     __restrict__ out) {
    const int lane = threadIdx.x & 63;
    const int w    = (blockIdx.x * blockDim.x + threadIdx.x) >> 6;
    if (w >= 3 * B_CNT) return;

    if (w < B_CNT) {
        const int u  = users[w];
        const int j0 = flags[u] - 1;
        if (j0 == w) return;
        const float2 v = ((const float2*)(out + (size_t)j0 * D_DIM))[lane];
        ((float2*)(out + (size_t)w * D_DIM))[lane] = v;
    } else {
        const int q   = w - B_CNT;
        const int idx = (q < B_CNT) ? pos_items[q] : neg_items[q - B_CNT];
        const float2 v = ((const float2*)(out + (size_t)(3 * B_CNT + idx) * D_DIM))[lane];
        ((float2*)(out + (size_t)w * D_DIM))[lane] = v;
    }
}

extern "C" void kernel_launch(void* const* d_in, const int* in_sizes, int n_in,
                              void* d_out, int out_size, void* d_ws, size_t ws_size,
                              hipStream_t stream) {
    const float* user_emb  = (const float*)d_in[0];
    const float* item_emb  = (const float*)d_in[1];
    const int*   adj_row   = (const int*)  d_in[2];
    const int*   adj_col   = (const int*)  d_in[3];
    const int*   users     = (const int*)  d_in[5];
    const int*   pos_items = (const int*)  d_in[6];
    const int*   neg_items = (const int*)  d_in[7];
    float* out = (float*)d_out;

    int* flags = (int*)d_ws;                                  // U
    int* icnt  = flags + U_CNT;                               // I
    int* ucnt  = icnt + I_CNT;                                // B
    int* udeg  = ucnt + B_CNT;                                // U
    float* dinv_u = (float*)(udeg + U_CNT);                   // U
    float* dinv_i = dinv_u + U_CNT;                           // I
    int* ibuck = (int*)(dinv_i + I_CNT);                      // I*ICAP
    int* ubuck = ibuck + (size_t)I_CNT * ICAP;                // B*UCAP
    unsigned* ue16 = (unsigned*)(ubuck + (size_t)B_CNT * UCAP); // U*64
    unsigned* ie16 = ue16 + (size_t)U_CNT * 64;                 // I*64

    hipMemsetAsync(flags, 0, (size_t)(2 * U_CNT + I_CNT + B_CNT) * sizeof(int), stream);

    rep_kernel<<<(B_CNT + 255) / 256, 256, 0, stream>>>(users, flags);

    cvt_kernel<<<(U_CNT * 64 + 255) / 256, 256, 0, stream>>>(user_emb, ue16, U_CNT * 64);
    cvt_kernel<<<(I_CNT * 64 + 255) / 256, 256, 0, stream>>>(item_emb, ie16, I_CNT * 64);

    bucket_kernel<<<(E_CNT / 2 + 255) / 256, 256, 0, stream>>>(
        adj_row, adj_col, flags, icnt, ucnt, udeg, ibuck, ubuck);

    dinv_kernel<<<(U_CNT + 255) / 256, 256, 0, stream>>>(udeg, icnt, dinv_u, dinv_i);

    item_gather_kernel<<<(I_CNT * 64 + 255) / 256, 256, 0, stream>>>(
        item_emb, ue16, icnt, dinv_u, dinv_i, ibuck, out);

    user_gather_kernel<<<(B_CNT * 64 + 255) / 256, 256, 0, stream>>>(
        user_emb, ie16, users, flags, ucnt, dinv_u, dinv_i, ubuck, out);

    finalize_kernel<<<(3 * B_CNT * 64 + 255) / 256, 256, 0, stream>>>(
        users, flags, pos_items, neg_items, out);
}

// Round 5
// 230.815 us; speedup vs baseline: 1.1472x; 1.1472x over previous
//
#include <hip/hip_runtime.h>
#include <hip/hip_bf16.h>

#define U_CNT 50000
#define I_CNT 25000
#define D_DIM 128
#define E_CNT 1000000
#define B_CNT 4096
#define ICAP 96          // max item degree ~68 (Poisson 40, 25K draws)
#define UCAP 64          // max user degree ~48 (Poisson 20, 50K draws)
#define BM_WORDS 1600    // ceil(U/32) = 1563, rounded

// ---------------------------------------------------------------------------
// ws layout (zeroed region first, ~323 KB memset):
//   bitmap [BM_WORDS] u32 : sampled-user bitmap (6.25 KB -> L1-resident)
//   slot   [U] int        : 0 or rep output slot+1 (read only on bitmap hit)
//   icnt   [I] int        : per-item bucket count
//   ucnt   [B] int        : per-rep-slot bucket count
// then:
//   ibuck  [I*ICAP] int2  : {user_col, val_bits}
//   ubuck  [B*UCAP] int2  : {item_col, val_bits}
//   ue16   [U*64]   u32   : user_emb as packed bf16x2 (256 B/row)
// total ~34.4 MB.
// ---------------------------------------------------------------------------

__device__ __forceinline__ unsigned pack_bf2(float lo, float hi) {
    __hip_bfloat16 a = __float2bfloat16(lo);   // RNE
    __hip_bfloat16 b = __float2bfloat16(hi);
    unsigned short ua = *reinterpret_cast<unsigned short*>(&a);
    unsigned short ub = *reinterpret_cast<unsigned short*>(&b);
    return ((unsigned)ub << 16) | ua;
}
__device__ __forceinline__ float bf_lo(unsigned w) { return __uint_as_float(w << 16); }
__device__ __forceinline__ float bf_hi(unsigned w) { return __uint_as_float(w & 0xffff0000u); }

// K1: mark sampled users (bitmap) + elect representative slot per user.
__global__ void rep_kernel(const int* __restrict__ users,
                           unsigned* __restrict__ bitmap,
                           int* __restrict__ slot) {
    int j = blockIdx.x * blockDim.x + threadIdx.x;
    if (j >= B_CNT) return;
    const int u = users[j];
    atomicOr(&bitmap[u >> 5], 1u << (u & 31));
    atomicCAS(&slot[u], 0, j + 1);
}

// K2: user_emb fp32 -> packed bf16x2 (streaming)
__global__ __launch_bounds__(256) void cvt_kernel(
        const float* __restrict__ src, unsigned* __restrict__ dst, int n_dw) {
    int i = blockIdx.x * blockDim.x + threadIdx.x;
    if (i >= n_dw) return;
    float2 f = ((const float2*)src)[i];
    dst[i] = pack_bf2(f.x, f.y);
}

// K3: one pass over the E undirected edges (mirror half of the COO arrays is
// redundant: adj_vals[j] == adj_vals[E+j]).  4 edges/thread, coalesced loads.
// Per edge: icnt atomic + 8B record store + L1 bitmap check (+8%: user side).
__global__ __launch_bounds__(256) void bucket_kernel(
        const int*      __restrict__ adj_row,
        const int*      __restrict__ adj_col,
        const float*    __restrict__ adj_vals,
        const unsigned* __restrict__ bitmap,
        const int*      __restrict__ slot,
        int*  __restrict__ icnt,  int*  __restrict__ ucnt,
        int2* __restrict__ ibuck, int2* __restrict__ ubuck) {
    const int base = (blockIdx.x * blockDim.x + threadIdx.x) * 4;
    if (base >= E_CNT) return;
    const int4   uu = *(const int4*)  (adj_row  + base);   // users
    const int4   tt = *(const int4*)  (adj_col  + base);   // items (+U)
    const float4 vv = *(const float4*)(adj_vals + base);

    const int   us[4] = {uu.x, uu.y, uu.z, uu.w};
    const int   ts[4] = {tt.x - U_CNT, tt.y - U_CNT, tt.z - U_CNT, tt.w - U_CNT};
    const float vs[4] = {vv.x, vv.y, vv.z, vv.w};

#pragma unroll
    for (int k = 0; k < 4; ++k) {
        const int u = us[k], t = ts[k];
        const int vb = __float_as_int(vs[k]);
        const int c = atomicAdd(&icnt[t], 1);
        ibuck[(size_t)t * ICAP + c] = make_int2(u, vb);
        if ((bitmap[u >> 5] >> (u & 31)) & 1u) {
            const int j0 = slot[u] - 1;
            const int c2 = atomicAdd(&ucnt[j0], 1);
            ubuck[(size_t)j0 * UCAP + c2] = make_int2(t, vb);
        }
    }
}

// K4: one wave per item; bf16 row gathers (1 dword/lane), fp32 accumulate,
// fused epilogue with fp32-exact ego term.
__global__ __launch_bounds__(256) void item_gather_kernel(
        const float*    __restrict__ item_emb,
        const unsigned* __restrict__ ue16,
        const int*      __restrict__ icnt,
        const int2*     __restrict__ ibuck,
        float*          __restrict__ out) {
    const int lane = threadIdx.x & 63;
    const int t    = (blockIdx.x * blockDim.x + threadIdx.x) >> 6;
    if (t >= I_CNT) return;

    const int   n = icnt[t];
    const int2* b = ibuck + (size_t)t * ICAP;
    float ax = 0.0f, ay = 0.0f;

    int p = 0;
    for (; p + 4 <= n; p += 4) {
        const int2 e0 = b[p], e1 = b[p + 1], e2 = b[p + 2], e3 = b[p + 3];
        const unsigned w0 = ue16[(size_t)e0.x * 64 + lane];
        const unsigned w1 = ue16[(size_t)e1.x * 64 + lane];
        const unsigned w2 = ue16[(size_t)e2.x * 64 + lane];
        const unsigned w3 = ue16[(size_t)e3.x * 64 + lane];
        const float v0 = __int_as_float(e0.y), v1 = __int_as_float(e1.y);
        const float v2 = __int_as_float(e2.y), v3 = __int_as_float(e3.y);
        ax += v0 * bf_lo(w0) + v1 * bf_lo(w1) + v2 * bf_lo(w2) + v3 * bf_lo(w3);
        ay += v0 * bf_hi(w0) + v1 * bf_hi(w1) + v2 * bf_hi(w2) + v3 * bf_hi(w3);
    }
    for (; p < n; ++p) {
        const int2 e = b[p];
        const unsigned w = ue16[(size_t)e.x * 64 + lane];
        const float v = __int_as_float(e.y);
        ax += v * bf_lo(w);
        ay += v * bf_hi(w);
    }

    const float2 eg = ((const float2*)(item_emb + (size_t)t * D_DIM))[lane];
    float2 o;
    o.x = (eg.x + 3.0f * ax) * 0.25f;
    o.y = (eg.y + 3.0f * ay) * 0.25f;
    ((float2*)(out + (size_t)(3 * B_CNT + t) * D_DIM))[lane] = o;
}

// K5: one wave per output slot; representatives compute (fp32 item gathers —
// only ~82K rows total, never the bottleneck), dups copied in finalize.
__global__ __launch_bounds__(256) void user_gather_kernel(
        const float* __restrict__ user_emb,
        const float* __restrict__ item_emb,
        const int*   __restrict__ users,
        const int*   __restrict__ slot,
        const int*   __restrict__ ucnt,
        const int2*  __restrict__ ubuck,
        float*       __restrict__ out) {
    const int lane = threadIdx.x & 63;
    const int j    = (blockIdx.x * blockDim.x + threadIdx.x) >> 6;
    if (j >= B_CNT) return;
    const int u = users[j];
    if (slot[u] - 1 != j) return;

    const int   n = ucnt[j];
    const int2* b = ubuck + (size_t)j * UCAP;
    float ax = 0.0f, ay = 0.0f;

    int p = 0;
    for (; p + 4 <= n; p += 4) {
        const int2 e0 = b[p], e1 = b[p + 1], e2 = b[p + 2], e3 = b[p + 3];
        const float2 x0 = ((const float2*)(item_emb + (size_t)e0.x * D_DIM))[lane];
        const float2 x1 = ((const float2*)(item_emb + (size_t)e1.x * D_DIM))[lane];
        const float2 x2 = ((const float2*)(item_emb + (size_t)e2.x * D_DIM))[lane];
        const float2 x3 = ((const float2*)(item_emb + (size_t)e3.x * D_DIM))[lane];
        const float v0 = __int_as_float(e0.y), v1 = __int_as_float(e1.y);
        const float v2 = __int_as_float(e2.y), v3 = __int_as_float(e3.y);
        ax += v0 * x0.x + v1 * x1.x + v2 * x2.x + v3 * x3.x;
        ay += v0 * x0.y + v1 * x1.y + v2 * x2.y + v3 * x3.y;
    }
    for (; p < n; ++p) {
        const int2 e = b[p];
        const float2 x = ((const float2*)(item_emb + (size_t)e.x * D_DIM))[lane];
        const float v = __int_as_float(e.y);
        ax += v * x.x;
        ay += v * x.y;
    }

    const float2 eg = ((const float2*)(user_emb + (size_t)u * D_DIM))[lane];
    float2 o;
    o.x = (eg.x + 3.0f * ax) * 0.25f;
    o.y = (eg.y + 3.0f * ay) * 0.25f;
    ((float2*)(out + (size_t)j * D_DIM))[lane] = o;
}

// K6: duplicate-user copies + pos/neg item gathers (read finished out rows).
__global__ __launch_bounds__(256) void finalize_kernel(
        const int* __restrict__ users,
        const int* __restrict__ slot,
        const int* __restrict__ pos_items,
        const int* __restrict__ neg_items,
        float*     __restrict__ out) {
    const int lane = threadIdx.x & 63;
    const int w    = (blockIdx.x * blockDim.x + threadIdx.x) >> 6;
    if (w >= 3 * B_CNT) return;

    if (w < B_CNT) {
        const int u  = users[w];
        const int j0 = slot[u] - 1;
        if (j0 == w) return;   // representative already written
        const float2 v = ((const float2*)(out + (size_t)j0 * D_DIM))[lane];
        ((float2*)(out + (size_t)w * D_DIM))[lane] = v;
    } else {
        const int q   = w - B_CNT;
        const int idx = (q < B_CNT) ? pos_items[q] : neg_items[q - B_CNT];
        const float2 v = ((const float2*)(out + (size_t)(3 * B_CNT + idx) * D_DIM))[lane];
        ((float2*)(out + (size_t)w * D_DIM))[lane] = v;
    }
}

extern "C" void kernel_launch(void* const* d_in, const int* in_sizes, int n_in,
                              void* d_out, int out_size, void* d_ws, size_t ws_size,
                              hipStream_t stream) {
    const float* user_emb  = (const float*)d_in[0];
    const float* item_emb  = (const float*)d_in[1];
    const int*   adj_row   = (const int*)  d_in[2];
    const int*   adj_col   = (const int*)  d_in[3];
    const float* adj_vals  = (const float*)d_in[4];
    const int*   users     = (const int*)  d_in[5];
    const int*   pos_items = (const int*)  d_in[6];
    const int*   neg_items = (const int*)  d_in[7];
    float* out = (float*)d_out;

    unsigned* bitmap = (unsigned*)d_ws;                        // BM_WORDS
    int* slot = (int*)(bitmap + BM_WORDS);                     // U
    int* icnt = slot + U_CNT;                                  // I
    int* ucnt = icnt + I_CNT;                                  // B
    int2* ibuck = (int2*)(ucnt + B_CNT);                       // I*ICAP
    int2* ubuck = ibuck + (size_t)I_CNT * ICAP;                // B*UCAP
    unsigned* ue16 = (unsigned*)(ubuck + (size_t)B_CNT * UCAP); // U*64

    // zero bitmap + slot + icnt + ucnt (contiguous, ~323 KB)
    hipMemsetAsync(bitmap, 0,
                   (size_t)(BM_WORDS + U_CNT + I_CNT + B_CNT) * sizeof(int),
                   stream);

    rep_kernel<<<(B_CNT + 255) / 256, 256, 0, stream>>>(users, bitmap, slot);

    cvt_kernel<<<(U_CNT * 64 + 255) / 256, 256, 0, stream>>>(
        user_emb, ue16, U_CNT * 64);

    bucket_kernel<<<(E_CNT / 4 + 255) / 256, 256, 0, stream>>>(
        adj_row, adj_col, adj_vals, bitmap, slot, icnt, ucnt, ibuck, ubuck);

    item_gather_kernel<<<(I_CNT * 64 + 255) / 256, 256, 0, stream>>>(
        item_emb, ue16, icnt, ibuck, out);

    user_gather_kernel<<<(B_CNT * 64 + 255) / 256, 256, 0, stream>>>(
        user_emb, item_emb, users, slot, ucnt, ubuck, out);

    finalize_kernel<<<(3 * B_CNT * 64 + 255) / 256, 256, 0, stream>>>(
        users, slot, pos_items, neg_items, out);
}